// Round 8
// baseline (241.587 us; speedup 1.0000x reference)
//
#include <hip/hip_runtime.h>

#define HW 4096
#define CCH 128
#define NB 4
#define MAGIC 0x5A17C0DEu

typedef short bf16x8 __attribute__((ext_vector_type(8)));
typedef float f32x4 __attribute__((ext_vector_type(4)));

__device__ __forceinline__ unsigned short f2bf(float f){
  union { float fv; unsigned u; } v; v.fv = f;
  unsigned r = v.u + 0x7fffu + ((v.u >> 16) & 1u);
  return (unsigned short)(r >> 16);
}
__device__ __forceinline__ float bf2f(unsigned short u){
  return __uint_as_float(((unsigned)u) << 16);
}
__device__ __forceinline__ f32x4 mfma16(bf16x8 a, bf16x8 b, f32x4 c){
  return __builtin_amdgcn_mfma_f32_16x16x32_bf16(a, b, c, 0, 0, 0);
}
// packed f32x2 -> bf16x2 (lo = a, hi = b)
__device__ __forceinline__ unsigned cvt_pk(float a, float b){
  unsigned r;
  asm("v_cvt_pk_bf16_f32 %0, %1, %2" : "=v"(r) : "v"(a), "v"(b));
  return r;
}
// async global->LDS, 16B/lane; LDS dest = wave-uniform base + lane*16
__device__ __forceinline__ void gll16(const void* g, void* l){
  __builtin_amdgcn_global_load_lds(
      (const __attribute__((address_space(1))) unsigned*)g,
      (__attribute__((address_space(3))) unsigned*)l, 16, 0, 0);
}

// ---------- Kernel 1: fused GN-stats + weight-prep + GN-apply + QKV ----------
// grid (64,NB,3) = 768 = exactly 3 blocks/CU (co-resident). Device-wide
// flag barrier: m==0 blocks publish partial GN stats + bf16 weights, everyone
// spins on 256 MAGIC flags (agent-scope acquire; poison-safe, no init needed).
__global__ __launch_bounds__(256, 3) void fused_k(const float* __restrict__ x,
    const float* __restrict__ sc, const float* __restrict__ bi,
    const float* __restrict__ wq, const float* __restrict__ wk,
    const float* __restrict__ wv, const float* __restrict__ wp,
    const float* __restrict__ bq, const float* __restrict__ bk,
    const float* __restrict__ bv,
    unsigned* __restrict__ flag, float* __restrict__ part,
    unsigned short* __restrict__ wqb, unsigned short* __restrict__ wkb,
    unsigned short* __restrict__ wvb, unsigned short* __restrict__ wpb,
    unsigned short* __restrict__ Qg, unsigned short* __restrict__ Kg,
    unsigned short* __restrict__ Vt){
  int lt = blockIdx.x, n = blockIdx.y, m = blockIdx.z, tid = threadIdx.x;
  int l0 = lt * 64;
  int w = tid >> 6, lane = tid & 63, l15 = lane & 15, g = lane >> 4;
  __shared__ __align__(16) char lds[49408];
  char* hA = lds;            // 16KB [64 l x 256B c], slot s holds c-chunk s^(l&15)
  char* WB = lds + 16384;    // 32KB weights [128 x 256B], slot s^(row&15)
  float2* sm = (float2*)(lds + 49152);  // stats per group (mean, rstd)

  // phase 0: x tile -> regs, per-group partial (sum, sumsq)
  float4 xv[8];
  #pragma unroll
  for (int i = 0; i < 8; i++){
    int c = (tid >> 4) + 16 * i, l4 = tid & 15;
    xv[i] = *(const float4*)&x[((size_t)(n * CCH + c)) * HW + l0 + l4 * 4];
  }
  if (m == 0){
    #pragma unroll
    for (int i = 0; i < 8; i++){
      float s = xv[i].x + xv[i].y + xv[i].z + xv[i].w;
      float q = xv[i].x * xv[i].x + xv[i].y * xv[i].y +
                xv[i].z * xv[i].z + xv[i].w * xv[i].w;
      #pragma unroll
      for (int d = 1; d < 64; d <<= 1){ s += __shfl_xor(s, d); q += __shfl_xor(q, d); }
      if (lane == 0){
        int grp = w + 4 * i;
        *(float2*)&part[((size_t)(n * 32 + grp) * 64 + lt) * 2] = make_float2(s, q);
      }
    }
    // weight fp32->bf16: block b64 handles 256 floats
    int b64 = lt + 64 * n;
    int idx = b64 * 256 + tid;
    int mat = idx >> 14, e = idx & 16383;
    const float* srcw = (mat == 0) ? wq : ((mat == 1) ? wk : ((mat == 2) ? wv : wp));
    unsigned short* dstw = (mat == 0) ? wqb : ((mat == 1) ? wkb : ((mat == 2) ? wvb : wpb));
    dstw[e] = f2bf(srcw[e]);
  }
  __syncthreads();   // drain this block's global stores
  if (m == 0 && tid == 0)
    __hip_atomic_store(&flag[lt + 64 * n], MAGIC, __ATOMIC_RELEASE,
                       __HIP_MEMORY_SCOPE_AGENT);
  {  // device-wide barrier: wait all 256 writer blocks (bounded spin)
    unsigned it = 0;
    while (__hip_atomic_load(&flag[tid], __ATOMIC_ACQUIRE,
                             __HIP_MEMORY_SCOPE_AGENT) != MAGIC){
      if (++it > 4000000u) break;
      __builtin_amdgcn_s_sleep(2);
    }
  }
  __syncthreads();

  // issue weight glls now (bf16 weights are ready)
  const unsigned short* wsrc = (m == 0) ? wqb : ((m == 1) ? wkb : wvb);
  const float* bsrc = (m == 0) ? bq : ((m == 1) ? bk : bv);
  {
    const char* wb2 = (const char*)wsrc;
    #pragma unroll
    for (int i = 0; i < 8; i++){
      int T = (8 * w + i) * 64 + lane;
      int row = T >> 4, c16 = (T & 15) ^ (row & 15);
      gll16(wb2 + row * 256 + c16 * 16, WB + (8 * w + i) * 1024);
    }
  }
  // reduce partials -> stats for this n (32 groups x 64 tiles)
  {
    int g2 = tid >> 3, k = tid & 7;
    float s = 0.f, q = 0.f;
    #pragma unroll
    for (int j = 0; j < 8; j++){
      float2 p = *(const float2*)&part[((size_t)(n * 32 + g2) * 64 + k * 8 + j) * 2];
      s += p.x; q += p.y;
    }
    #pragma unroll
    for (int d = 1; d < 8; d <<= 1){ s += __shfl_xor(s, d); q += __shfl_xor(q, d); }
    if (k == 0){
      float mean = s * (1.f / 16384.f);
      float var  = q * (1.f / 16384.f) - mean * mean;
      sm[g2] = make_float2(mean, rsqrtf(var + 1e-5f));
    }
  }
  __syncthreads();   // stats ready (also drains weight glls)
  // GN apply from regs -> swizzled bf16 hA
  #pragma unroll
  for (int i = 0; i < 8; i++){
    int c = (tid >> 4) + 16 * i, l4 = tid & 15;
    float2 st = sm[c >> 2];
    float scl = st.y * sc[c];
    float off = bi[c] - st.x * scl;
    float rv[4] = { xv[i].x * scl + off, xv[i].y * scl + off,
                    xv[i].z * scl + off, xv[i].w * scl + off };
    #pragma unroll
    for (int j = 0; j < 4; j++){
      int l = l4 * 4 + j;
      int slot = (c >> 3) ^ (l & 15);
      *(unsigned short*)(hA + l * 256 + slot * 16 + ((c & 7) << 1)) = f2bf(rv[j]);
    }
  }
  __syncthreads();
  // matmul: [64 l x 128 c] x W^T -> 64 x 128
  bf16x8 a[4];
  #pragma unroll
  for (int kc = 0; kc < 4; kc++)
    a[kc] = *(const bf16x8*)(hA + (16 * w + l15) * 256 + ((4 * kc + g) ^ l15) * 16);
  f32x4 acc[8];
  #pragma unroll
  for (int ct = 0; ct < 8; ct++) acc[ct] = (f32x4)(0.f);
  #pragma unroll
  for (int ct = 0; ct < 8; ct++)
    #pragma unroll
    for (int kc = 0; kc < 4; kc++){
      bf16x8 bfr = *(const bf16x8*)(WB + (16 * ct + l15) * 256 + ((4 * kc + g) ^ l15) * 16);
      acc[ct] = mfma16(a[kc], bfr, acc[ct]);
    }
  __syncthreads();   // WB reads done; reuse as output-stage LDS
  if (m < 2){
    float qs = (m == 0) ? 0.08838834764831845f : 1.0f;  // 128^-0.5 folded into Q
    unsigned short* dst = (m == 0) ? Qg : Kg;
    unsigned short* os = (unsigned short*)(lds + 16384);  // [64][136]
    #pragma unroll
    for (int ct = 0; ct < 8; ct++){
      int o = 16 * ct + l15;
      float bias = bsrc[o];
      #pragma unroll
      for (int r = 0; r < 4; r++)
        os[(16 * w + 4 * g + r) * 136 + o] = f2bf((acc[ct][r] + bias) * qs);
    }
    __syncthreads();
    #pragma unroll
    for (int i = 0; i < 4; i++){
      int T = tid + 256 * i;
      int row = T >> 4, cb = T & 15;
      *(uint4*)&dst[((size_t)(n * HW) + l0 + row) * CCH + cb * 8] =
          *(const uint4*)&os[row * 136 + cb * 8];
    }
  } else {
    unsigned short* os = (unsigned short*)(lds + 16384);  // [128][72]
    #pragma unroll
    for (int ct = 0; ct < 8; ct++){
      int o = 16 * ct + l15;
      float bias = bsrc[o];
      #pragma unroll
      for (int r = 0; r < 4; r++)
        os[o * 72 + 16 * w + 4 * g + r] = f2bf(acc[ct][r] + bias);
    }
    __syncthreads();
    #pragma unroll
    for (int i = 0; i < 4; i++){
      int T = tid + 256 * i;
      int row = T >> 3, c = T & 7;
      *(uint4*)&Vt[((size_t)(n * CCH) + row) * HW + l0 + c * 8] =
          *(const uint4*)&os[row * 72 + c * 8];
    }
  }
}

// ---------- Kernel 2: flash attention, 32 q-rows/wave, dbuf, 1 barrier ------
// Swapped-operand QK (mfma(K,Q)); each kf/vf LDS read feeds BOTH q-subtiles.
// P via per-wave LDS (cvt_pk + 8 ds_write_b32, 2 ds_read_b128; in-order DS).
// LDS 2x32KB dbuf + 9KB P = 73KB -> 2 blocks/CU.
__global__ __launch_bounds__(256, 2) void attn_k(const unsigned short* __restrict__ Qg,
    const unsigned short* __restrict__ Kg, const unsigned short* __restrict__ Vt,
    unsigned short* __restrict__ Op, float* __restrict__ Ml, int lsp){
  int nbk = gridDim.x, cpx = nbk >> 3, b = blockIdx.x;
  int swz = (b & 7) * cpx + (b >> 3);
  int qt = swz & 31;
  int rest = swz >> 5;
  int splits = 1 << lsp;
  int sp = rest & (splits - 1);
  int n = rest >> lsp;
  int q0 = qt * 128;
  int kvs = HW >> lsp;
  int nt = kvs >> 6;                 // 64-kv tiles
  int tid = threadIdx.x;
  int w = tid >> 6, lane = tid & 63, l15 = lane & 15, g = lane >> 4;
  __shared__ __align__(16) char lds[74752];   // 2 x (K16K + V16K) + P 9K
  char* Pw = lds + 65536 + w * 2304;          // per-wave P [16 q][144B]

  int qb = q0 + w * 32;
  bf16x8 qf0[4], qf1[4];
  #pragma unroll
  for (int kc = 0; kc < 4; kc++){
    qf0[kc] = *(const bf16x8*)&Qg[((size_t)(n * HW) + qb + l15) * CCH + 32 * kc + 8 * g];
    qf1[kc] = *(const bf16x8*)&Qg[((size_t)(n * HW) + qb + 16 + l15) * CCH + 32 * kc + 8 * g];
  }
  f32x4 ov0[8], ov1[8];
  #pragma unroll
  for (int i = 0; i < 8; i++){ ov0[i] = (f32x4)(0.f); ov1[i] = (f32x4)(0.f); }
  float mr0 = -3.0e38f, lr0 = 0.f, mr1 = -3.0e38f, lr1 = 0.f;

  const char* kp[4]; const char* vp[4];
  {
    const char* kbase = (const char*)Kg + ((size_t)(n * HW) + sp * kvs) * (CCH * 2);
    const char* vbase = (const char*)Vt + (size_t)(n * CCH) * (HW * 2) + (size_t)sp * kvs * 2;
    #pragma unroll
    for (int i = 0; i < 4; i++){
      int C = (w * 4 + i) * 64 + lane;
      int kr = C >> 4, ks = (C & 15) ^ (kr & 15);
      kp[i] = kbase + kr * 256 + ks * 16;
      int vr = C >> 3, c8 = (C & 7) ^ (vr & 7);
      vp[i] = vbase + (size_t)vr * (HW * 2) + c8 * 16;
    }
  }
  // prologue: tile 0 -> buffer 0
  #pragma unroll
  for (int i = 0; i < 4; i++){
    gll16(kp[i], lds + w * 4096 + i * 1024);
    gll16(vp[i], lds + 16384 + w * 4096 + i * 1024);
  }
  __syncthreads();

  for (int t = 0; t < nt; t++){
    char* cur = lds + ((t & 1) << 15);
    if (t + 1 < nt){
      char* nb = lds + (((t + 1) & 1) << 15);
      #pragma unroll
      for (int i = 0; i < 4; i++){
        gll16(kp[i] + (size_t)(t + 1) * 16384, nb + w * 4096 + i * 1024);
        gll16(vp[i] + (size_t)(t + 1) * 128,   nb + 16384 + w * 4096 + i * 1024);
      }
    }
    char* Ks = cur; char* Vs = cur + 16384;

    // S for both q-subtiles; kf reads shared
    f32x4 s0[4], s1[4];
    __builtin_amdgcn_s_setprio(1);
    #pragma unroll
    for (int ct = 0; ct < 4; ct++){
      f32x4 a0 = (f32x4)(0.f), a1 = (f32x4)(0.f);
      #pragma unroll
      for (int kc = 0; kc < 4; kc++){
        bf16x8 kf = *(const bf16x8*)(Ks + (16 * ct + l15) * 256 + (((4 * kc + g) ^ l15) << 4));
        a0 = mfma16(kf, qf0[kc], a0);
        a1 = mfma16(kf, qf1[kc], a1);
      }
      s0[ct] = a0; s1[ct] = a1;
    }
    __builtin_amdgcn_s_setprio(0);

    // softmax qs0 (in-lane 16 scores + 2 shfl), defer-rescale THR=8
    float mx0 = -3.0e38f, mx1 = -3.0e38f;
    #pragma unroll
    for (int ct = 0; ct < 4; ct++)
      #pragma unroll
      for (int r = 0; r < 4; r++){
        mx0 = fmaxf(mx0, s0[ct][r]);
        mx1 = fmaxf(mx1, s1[ct][r]);
      }
    mx0 = fmaxf(mx0, __shfl_xor(mx0, 16)); mx0 = fmaxf(mx0, __shfl_xor(mx0, 32));
    mx1 = fmaxf(mx1, __shfl_xor(mx1, 16)); mx1 = fmaxf(mx1, __shfl_xor(mx1, 32));
    if (__any(mx0 > mr0 + 8.0f)){
      float mn = fmaxf(mr0, mx0);
      float al = __expf(mr0 - mn);
      mr0 = mn; lr0 *= al;
      #pragma unroll
      for (int ct = 0; ct < 8; ct++)
        #pragma unroll
        for (int r = 0; r < 4; r++) ov0[ct][r] *= al;
    }
    if (__any(mx1 > mr1 + 8.0f)){
      float mn = fmaxf(mr1, mx1);
      float al = __expf(mr1 - mn);
      mr1 = mn; lr1 *= al;
      #pragma unroll
      for (int ct = 0; ct < 8; ct++)
        #pragma unroll
        for (int r = 0; r < 4; r++) ov1[ct][r] *= al;
    }
    float rs0 = 0.f, rs1 = 0.f;
    #pragma unroll
    for (int ct = 0; ct < 4; ct++)
      #pragma unroll
      for (int r = 0; r < 4; r++){
        float e0 = __expf(s0[ct][r] - mr0); s0[ct][r] = e0; rs0 += e0;
        float e1 = __expf(s1[ct][r] - mr1); s1[ct][r] = e1; rs1 += e1;
      }
    rs0 += __shfl_xor(rs0, 16); rs0 += __shfl_xor(rs0, 32); lr0 += rs0;
    rs1 += __shfl_xor(rs1, 16); rs1 += __shfl_xor(rs1, 32); lr1 += rs1;

    // qs0: pack -> P, read pb0 (DS in-order per wave; no barrier)
    bf16x8 pb0[2], pb1[2];
    #pragma unroll
    for (int ct = 0; ct < 4; ct++)
      #pragma unroll
      for (int h = 0; h < 2; h++)
        *(unsigned*)(Pw + l15 * 144 + (8 * ct + 2 * g + h) * 4) =
            cvt_pk(s0[ct][2 * h], s0[ct][2 * h + 1]);
    #pragma unroll
    for (int kc = 0; kc < 2; kc++)
      pb0[kc] = *(const bf16x8*)(Pw + l15 * 144 + (16 * kc + 4 * g) * 4);
    // qs1: same buffer (write-after-read ordered by in-order DS pipe)
    #pragma unroll
    for (int ct = 0; ct < 4; ct++)
      #pragma unroll
      for (int h = 0; h < 2; h++)
        *(unsigned*)(Pw + l15 * 144 + (8 * ct + 2 * g + h) * 4) =
            cvt_pk(s1[ct][2 * h], s1[ct][2 * h + 1]);
    #pragma unroll
    for (int kc = 0; kc < 2; kc++)
      pb1[kc] = *(const bf16x8*)(Pw + l15 * 144 + (16 * kc + 4 * g) * 4);

    // PV: vf reads shared across both q-subtiles
    __builtin_amdgcn_s_setprio(1);
    #pragma unroll
    for (int ct = 0; ct < 8; ct++){
      int row = 16 * ct + l15;
      #pragma unroll
      for (int kc = 0; kc < 2; kc++){
        bf16x8 vf = *(const bf16x8*)(Vs + row * 128 + (((4 * kc + g) ^ (l15 & 7)) << 4));
        ov0[ct] = mfma16(vf, pb0[kc], ov0[ct]);
        ov1[ct] = mfma16(vf, pb1[kc], ov1[ct]);
      }
    }
    __builtin_amdgcn_s_setprio(0);
    __syncthreads();   // drains prefetch; hands buffers over
  }
  // epilogue: unnormalized O~ + (m, l) for both q-subtiles
  size_t obase = (size_t)((sp * NB + n) * HW);
  size_t qr0 = obase + qb + l15, qr1 = qr0 + 16;
  #pragma unroll
  for (int ct = 0; ct < 8; ct++){
    ushort4 p0, p1;
    p0.x = f2bf(ov0[ct][0]); p0.y = f2bf(ov0[ct][1]);
    p0.z = f2bf(ov0[ct][2]); p0.w = f2bf(ov0[ct][3]);
    p1.x = f2bf(ov1[ct][0]); p1.y = f2bf(ov1[ct][1]);
    p1.z = f2bf(ov1[ct][2]); p1.w = f2bf(ov1[ct][3]);
    *(ushort4*)&Op[qr0 * CCH + 16 * ct + 4 * g] = p0;
    *(ushort4*)&Op[qr1 * CCH + 16 * ct + 4 * g] = p1;
  }
  if (g == 0){
    Ml[qr0 * 2] = mr0; Ml[qr0 * 2 + 1] = lr0;
    Ml[qr1 * 2] = mr1; Ml[qr1 * 2 + 1] = lr1;
  }
}

// ---------- Kernel 3: combine splits + output projection + residual ---------
__global__ __launch_bounds__(256) void projout_k(const unsigned short* __restrict__ Op,
    const float* __restrict__ Ml, const unsigned short* __restrict__ wpb,
    const float* __restrict__ bp, const float* __restrict__ x,
    float* __restrict__ out, int splits){
  int n = blockIdx.y, l0 = blockIdx.x * 32, tid = threadIdx.x;
  int w = tid >> 6, lane = tid & 63, l15 = lane & 15, g = lane >> 4;
  __shared__ __align__(16) unsigned short hs[32][136];
  __shared__ __align__(16) char WB[32768];
  {
    const char* wb2 = (const char*)wpb;
    #pragma unroll
    for (int i = 0; i < 8; i++){
      int T = (8 * w + i) * 64 + lane;
      int row = T >> 4, c16 = (T & 15) ^ (row & 15);
      gll16(wb2 + row * 256 + c16 * 16, WB + (8 * w + i) * 1024);
    }
  }
  const size_t SSTR = (size_t)NB * HW;
  #pragma unroll
  for (int i = 0; i < 2; i++){
    int T = tid + 256 * i;
    int row = T >> 4, cb = (T & 15) * 8;
    size_t gl = (size_t)n * HW + l0 + row;
    float mv = -3.0e38f;
    #pragma unroll
    for (int s = 0; s < 4; s++)
      if (s < splits) mv = fmaxf(mv, Ml[(s * SSTR + gl) * 2]);
    float fa[8];
    #pragma unroll
    for (int j = 0; j < 8; j++) fa[j] = 0.f;
    float denom = 0.f;
    #pragma unroll
    for (int s = 0; s < 4; s++){
      if (s < splits){
        float wgt = __expf(Ml[(s * SSTR + gl) * 2] - mv);
        denom += wgt * Ml[(s * SSTR + gl) * 2 + 1];
        uint4 a = *(const uint4*)&Op[(s * SSTR + gl) * CCH + cb];
        const unsigned short* au = (const unsigned short*)&a;
        #pragma unroll
        for (int j = 0; j < 8; j++) fa[j] += wgt * bf2f(au[j]);
      }
    }
    float inv = 1.f / denom;
    #pragma unroll
    for (int j = 0; j < 8; j++) hs[row][cb + j] = f2bf(fa[j] * inv);
  }
  __syncthreads();
  int rt = w & 1, cg = w >> 1;
  bf16x8 a[4];
  #pragma unroll
  for (int kc = 0; kc < 4; kc++)
    a[kc] = *reinterpret_cast<const bf16x8*>(&hs[16 * rt + l15][32 * kc + 8 * g]);
  f32x4 acc[4];
  #pragma unroll
  for (int ci = 0; ci < 4; ci++) acc[ci] = (f32x4)(0.f);
  #pragma unroll
  for (int ci = 0; ci < 4; ci++){
    int o = 16 * (cg * 4 + ci) + l15;
    #pragma unroll
    for (int kc = 0; kc < 4; kc++){
      bf16x8 bfr = *(const bf16x8*)(WB + o * 256 + ((4 * kc + g) ^ l15) * 16);
      acc[ci] = mfma16(a[kc], bfr, acc[ci]);
    }
  }
  #pragma unroll
  for (int ci = 0; ci < 4; ci++){
    int o = 16 * (cg * 4 + ci) + l15;
    float bias = bp[o];
    size_t base = ((size_t)(n * CCH) + o) * HW + l0 + 16 * rt + 4 * g;
    float4 xr = *(const float4*)&x[base];
    float4 res;
    res.x = xr.x + acc[ci][0] + bias;
    res.y = xr.y + acc[ci][1] + bias;
    res.z = xr.z + acc[ci][2] + bias;
    res.w = xr.w + acc[ci][3] + bias;
    *(float4*)&out[base] = res;
  }
}

extern "C" void kernel_launch(void* const* d_in, const int* in_sizes, int n_in,
                              void* d_out, int out_size, void* d_ws, size_t ws_size,
                              hipStream_t stream){
  const float* x    = (const float*)d_in[0];
  const float* gnsc = (const float*)d_in[1];
  const float* gnb  = (const float*)d_in[2];
  const float* wq   = (const float*)d_in[3];
  const float* bq   = (const float*)d_in[4];
  const float* wk   = (const float*)d_in[5];
  const float* bk   = (const float*)d_in[6];
  const float* wv   = (const float*)d_in[7];
  const float* bv   = (const float*)d_in[8];
  const float* wp   = (const float*)d_in[9];
  const float* bp   = (const float*)d_in[10];
  float* out = (float*)d_out;

  char* ws = (char*)d_ws;
  const size_t BUF = (size_t)NB * HW * CCH * sizeof(unsigned short);  // 4 MiB
  const size_t PARTOFF = 4096;                  // flags in [0,1KB)
  const size_t WOFF2 = PARTOFF + 65536;         // partial stats 64KB
  const size_t QOFF = 204800;                   // after 4 bf16 weight mats
  const size_t NEED4 = QOFF + 7 * BUF + (size_t)4 * NB * HW * 2 * sizeof(float);
  const int lsp = (ws_size >= NEED4) ? 2 : 1;
  const int splits = 1 << lsp;

  unsigned* flag      = (unsigned*)ws;
  float* part         = (float*)(ws + PARTOFF);
  unsigned short* wqb = (unsigned short*)(ws + WOFF2);
  unsigned short* wkb = (unsigned short*)(ws + WOFF2 + 32768);
  unsigned short* wvb = (unsigned short*)(ws + WOFF2 + 65536);
  unsigned short* wpb = (unsigned short*)(ws + WOFF2 + 98304);
  unsigned short* Qg  = (unsigned short*)(ws + QOFF);
  unsigned short* Kg  = (unsigned short*)(ws + QOFF + BUF);
  unsigned short* Vt  = (unsigned short*)(ws + QOFF + 2 * BUF);
  unsigned short* Op  = (unsigned short*)(ws + QOFF + 3 * BUF);
  float*          Ml  = (float*)(ws + QOFF + 3 * BUF + (size_t)splits * BUF);

  fused_k<<<dim3(64, NB, 3), 256, 0, stream>>>(x, gnsc, gnb, wq, wk, wv, wp,
      bq, bk, bv, flag, part, wqb, wkb, wvb, wpb, Qg, Kg, Vt);
  attn_k<<<dim3(32 * NB * splits), 256, 0, stream>>>(Qg, Kg, Vt, Op, Ml, lsp);
  projout_k<<<dim3(128, NB), 256, 0, stream>>>(Op, Ml, wpb, bp, x, out, splits);
}

// Round 9
// 174.186 us; speedup vs baseline: 1.3869x; 1.3869x over previous
//
#include <hip/hip_runtime.h>

#define HW 4096
#define CCH 128
#define NB 4

typedef short bf16x8 __attribute__((ext_vector_type(8)));
typedef float f32x4 __attribute__((ext_vector_type(4)));

__device__ __forceinline__ unsigned short f2bf(float f){
  union { float fv; unsigned u; } v; v.fv = f;
  unsigned r = v.u + 0x7fffu + ((v.u >> 16) & 1u);
  return (unsigned short)(r >> 16);
}
__device__ __forceinline__ float bf2f(unsigned short u){
  return __uint_as_float(((unsigned)u) << 16);
}
__device__ __forceinline__ f32x4 mfma16(bf16x8 a, bf16x8 b, f32x4 c){
  return __builtin_amdgcn_mfma_f32_16x16x32_bf16(a, b, c, 0, 0, 0);
}
// async global->LDS, 16B/lane; LDS dest = wave-uniform base + lane*16
__device__ __forceinline__ void gll16(const void* g, void* l){
  __builtin_amdgcn_global_load_lds(
      (const __attribute__((address_space(1))) unsigned*)g,
      (__attribute__((address_space(3))) unsigned*)l, 16, 0, 0);
}

// ---------- Kernel A: group-norm stats + weight fp32->bf16 prep ----------
__global__ __launch_bounds__(256) void gn_stats_k(const float* __restrict__ x,
    float* __restrict__ stats,
    const float* __restrict__ wq, const float* __restrict__ wk,
    const float* __restrict__ wv, const float* __restrict__ wp,
    unsigned short* __restrict__ wqb, unsigned short* __restrict__ wkb,
    unsigned short* __restrict__ wvb, unsigned short* __restrict__ wpb){
  int tid = threadIdx.x;
  if (tid < 128){
    int f4 = blockIdx.x * 128 + tid;
    int m = f4 >> 12, e = f4 & 4095;
    const float* s4 = (m == 0) ? wq : ((m == 1) ? wk : ((m == 2) ? wv : wp));
    unsigned short* d4 = (m == 0) ? wqb : ((m == 1) ? wkb : ((m == 2) ? wvb : wpb));
    float4 v = *(const float4*)(s4 + e * 4);
    ushort4 b; b.x = f2bf(v.x); b.y = f2bf(v.y); b.z = f2bf(v.z); b.w = f2bf(v.w);
    *(ushort4*)(d4 + e * 4) = b;
  }
  int gid = blockIdx.x;
  const float4* p = (const float4*)(x + (size_t)gid * 16384);
  float s = 0.f, q = 0.f;
  #pragma unroll
  for (int i = 0; i < 16; i++){
    float4 v = p[tid + 256 * i];
    s += v.x + v.y + v.z + v.w;
    q += v.x * v.x + v.y * v.y + v.z * v.z + v.w * v.w;
  }
  #pragma unroll
  for (int d = 1; d < 64; d <<= 1){ s += __shfl_xor(s, d); q += __shfl_xor(q, d); }
  __shared__ float red[8];
  int w = tid >> 6;
  if ((tid & 63) == 0){ red[2 * w] = s; red[2 * w + 1] = q; }
  __syncthreads();
  if (tid == 0){
    float S = red[0] + red[2] + red[4] + red[6];
    float Q = red[1] + red[3] + red[5] + red[7];
    float mean = S * (1.f / 16384.f);
    float var  = Q * (1.f / 16384.f) - mean * mean;
    stats[2 * gid]     = mean;
    stats[2 * gid + 1] = rsqrtf(var + 1e-5f);
  }
}

// ---------- Kernel B: fused GN-apply + QKV projection (R7, proven) ----------
__global__ __launch_bounds__(256, 3) void gnqkv_k(const float* __restrict__ x,
    const float* __restrict__ stats, const float* __restrict__ sc,
    const float* __restrict__ bi,
    const unsigned short* __restrict__ wqb, const unsigned short* __restrict__ wkb,
    const unsigned short* __restrict__ wvb,
    const float* __restrict__ bq, const float* __restrict__ bk,
    const float* __restrict__ bv,
    unsigned short* __restrict__ Qg, unsigned short* __restrict__ Kg,
    unsigned short* __restrict__ Vt){
  int n = blockIdx.y, l0 = blockIdx.x * 64, m = blockIdx.z, tid = threadIdx.x;
  int w = tid >> 6, lane = tid & 63, l15 = lane & 15, g = lane >> 4;
  __shared__ __align__(16) char lds[49152];
  char* hA = lds;            // 16KB [64 l x 256B c], slot s holds c-chunk s^(l&15)
  char* WB = lds + 16384;    // 32KB [128 x 256B], slot s^(row&15)
  const unsigned short* wsrc = (m == 0) ? wqb : ((m == 1) ? wkb : wvb);
  const float* bsrc = (m == 0) ? bq : ((m == 1) ? bk : bv);
  {
    const char* wb2 = (const char*)wsrc;
    #pragma unroll
    for (int i = 0; i < 8; i++){
      int T = (8 * w + i) * 64 + lane;
      int row = T >> 4, c16 = (T & 15) ^ (row & 15);
      gll16(wb2 + row * 256 + c16 * 16, WB + (8 * w + i) * 1024);
    }
  }
  #pragma unroll
  for (int i = 0; i < 8; i++){
    int F = tid + 256 * i;
    int c = F >> 4, l4 = F & 15;
    float4 v = *(const float4*)&x[((size_t)(n * CCH + c)) * HW + l0 + l4 * 4];
    int grp = n * 32 + (c >> 2);
    float mean = stats[2 * grp], rstd = stats[2 * grp + 1];
    float scl = rstd * sc[c];
    float off = bi[c] - mean * scl;
    float r0 = v.x * scl + off, r1 = v.y * scl + off;
    float r2 = v.z * scl + off, r3 = v.w * scl + off;
    #pragma unroll
    for (int j = 0; j < 4; j++){
      int l = l4 * 4 + j;
      float rv = (j == 0) ? r0 : ((j == 1) ? r1 : ((j == 2) ? r2 : r3));
      int slot = (c >> 3) ^ (l & 15);
      *(unsigned short*)(hA + l * 256 + slot * 16 + ((c & 7) << 1)) = f2bf(rv);
    }
  }
  __syncthreads();
  bf16x8 a[4];
  #pragma unroll
  for (int kc = 0; kc < 4; kc++)
    a[kc] = *(const bf16x8*)(hA + (16 * w + l15) * 256 + ((4 * kc + g) ^ l15) * 16);
  f32x4 acc[8];
  #pragma unroll
  for (int ct = 0; ct < 8; ct++) acc[ct] = (f32x4)(0.f);
  #pragma unroll
  for (int ct = 0; ct < 8; ct++)
    #pragma unroll
    for (int kc = 0; kc < 4; kc++){
      bf16x8 bfr = *(const bf16x8*)(WB + (16 * ct + l15) * 256 + ((4 * kc + g) ^ l15) * 16);
      acc[ct] = mfma16(a[kc], bfr, acc[ct]);
    }
  __syncthreads();   // WB reads done; reuse as output-stage LDS
  if (m < 2){
    // Q pre-scale folds 128^-0.5 AND log2(e): softmax runs in exp2 domain
    float qs = (m == 0) ? (0.08838834764831845f * 1.4426950408889634f) : 1.0f;
    unsigned short* dst = (m == 0) ? Qg : Kg;
    unsigned short* os = (unsigned short*)(lds + 16384);  // [64][136]
    #pragma unroll
    for (int ct = 0; ct < 8; ct++){
      int o = 16 * ct + l15;
      float bias = bsrc[o];
      #pragma unroll
      for (int r = 0; r < 4; r++)
        os[(16 * w + 4 * g + r) * 136 + o] = f2bf((acc[ct][r] + bias) * qs);
    }
    __syncthreads();
    #pragma unroll
    for (int i = 0; i < 4; i++){
      int T = tid + 256 * i;
      int row = T >> 4, cb = T & 15;
      *(uint4*)&dst[((size_t)(n * HW) + l0 + row) * CCH + cb * 8] =
          *(const uint4*)&os[row * 136 + cb * 8];
    }
  } else {
    unsigned short* os = (unsigned short*)(lds + 16384);  // [128][72]
    #pragma unroll
    for (int ct = 0; ct < 8; ct++){
      int o = 16 * ct + l15;
      float bias = bsrc[o];
      #pragma unroll
      for (int r = 0; r < 4; r++)
        os[o * 72 + 16 * w + 4 * g + r] = f2bf(acc[ct][r] + bias);
    }
    __syncthreads();
    #pragma unroll
    for (int i = 0; i < 4; i++){
      int T = tid + 256 * i;
      int row = T >> 3, c = T & 7;
      *(uint4*)&Vt[((size_t)(n * CCH) + row) * HW + l0 + c * 8] =
          *(const uint4*)&os[row * 72 + c * 8];
    }
  }
}

// ---------- Kernel D: flash attention (R6 68µs structure + exp2 + splits) ---
// Swapped-operand QK^T = mfma(K,Q): lane holds S[q=l15][kv=16ct+4g+r] in
// log2 domain; softmax in-lane + 2 shfl; P in regs via 16 shfl; PV =
// mfma(V^T,P). 32KB LDS, 2 barriers/iter. launch_bounds(256,5): 5 x 32KB =
// exactly 160KB LDS -> up to 5 blocks/CU when grid is deep (splits=8).
__global__ __launch_bounds__(256, 5) void attn_k(const unsigned short* __restrict__ Qg,
    const unsigned short* __restrict__ Kg, const unsigned short* __restrict__ Vt,
    unsigned short* __restrict__ Op, float* __restrict__ Ml, int lsp){
  int nbk = gridDim.x, cpx = nbk >> 3, b = blockIdx.x;
  int swz = (b & 7) * cpx + (b >> 3);
  int q0 = (swz & 63) * 64;
  int rest = swz >> 6;
  int splits = 1 << lsp;
  int sp = rest & (splits - 1);
  int n = rest >> lsp;
  int kvs = HW >> lsp, nt = 64 >> lsp;
  int tid = threadIdx.x;
  int w = tid >> 6, lane = tid & 63, l15 = lane & 15, g = lane >> 4;
  __shared__ __align__(16) char lds[32768];
  char* Ks = lds;            // 16 KB [64 x 256B], chunk swz c^(row&15)
  char* Vs = lds + 16384;    // 16 KB [128 x 128B], chunk swz c^(row&7)
  const float THR = 8.0f * 1.4426950408889634f;   // defer-rescale, log2 domain

  bf16x8 qf[4];   // lane holds Q[q=16w+l15][c=32kc+8g..] (log2e-prescaled)
  #pragma unroll
  for (int kc = 0; kc < 4; kc++)
    qf[kc] = *reinterpret_cast<const bf16x8*>(
        &Qg[((size_t)(n * HW) + q0 + 16 * w + l15) * CCH + 32 * kc + 8 * g]);
  f32x4 ov[8];    // ov[ct][r] = O[q][c=16ct+4g+r] (unnormalized)
  #pragma unroll
  for (int i = 0; i < 8; i++) ov[i] = (f32x4)(0.f);
  float mrun = -3.0e38f, lrun = 0.f;

  const char* kp[4]; const char* vp[4];
  {
    const char* kbase = (const char*)Kg + ((size_t)(n * HW) + sp * kvs) * (CCH * 2);
    const char* vbase = (const char*)Vt + (size_t)(n * CCH) * (HW * 2) + (size_t)sp * kvs * 2;
    #pragma unroll
    for (int i = 0; i < 4; i++){
      int C = (w * 4 + i) * 64 + lane;
      int row = C >> 4, c16 = (C & 15) ^ (row & 15);
      kp[i] = kbase + row * 256 + c16 * 16;
      int vrow = C >> 3, c8 = (C & 7) ^ (vrow & 7);
      vp[i] = vbase + (size_t)vrow * (HW * 2) + c8 * 16;
    }
  }
  char* kl = Ks + w * 4096;
  char* vl = Vs + w * 4096;

  for (int t = 0; t < nt; t++){
    __syncthreads();                 // B1: prev iter done with Ks/Vs
    #pragma unroll
    for (int i = 0; i < 4; i++) gll16(kp[i] + (size_t)t * 16384, kl + i * 1024);
    #pragma unroll
    for (int i = 0; i < 4; i++) gll16(vp[i] + (size_t)t * 128,   vl + i * 1024);
    __syncthreads();                 // B2: K/V tile visible

    // S^T (log2 domain): s[ct][r] = S[q][kv=16ct+4g+r]
    f32x4 s[4];
    __builtin_amdgcn_s_setprio(1);
    #pragma unroll
    for (int ct = 0; ct < 4; ct++){
      f32x4 acc = (f32x4)(0.f);
      #pragma unroll
      for (int kc = 0; kc < 4; kc++){
        bf16x8 kf = *(const bf16x8*)(Ks + (16 * ct + l15) * 256 + (((4 * kc + g) ^ l15) << 4));
        acc = mfma16(kf, qf[kc], acc);   // swapped operands
      }
      s[ct] = acc;
    }
    __builtin_amdgcn_s_setprio(0);

    // in-lane softmax (16 scores) + 2-shfl reduce; exp2 throughout
    float mx = -3.0e38f;
    #pragma unroll
    for (int ct = 0; ct < 4; ct++)
      #pragma unroll
      for (int r = 0; r < 4; r++) mx = fmaxf(mx, s[ct][r]);
    mx = fmaxf(mx, __shfl_xor(mx, 16));
    mx = fmaxf(mx, __shfl_xor(mx, 32));
    if (__any(mx > mrun + THR)){     // defer-rescale
      float mn = fmaxf(mrun, mx);
      float al = exp2f(mrun - mn);
      mrun = mn; lrun *= al;
      #pragma unroll
      for (int ct = 0; ct < 8; ct++)
        #pragma unroll
        for (int r = 0; r < 4; r++) ov[ct][r] *= al;
    }
    float rs = 0.f;
    #pragma unroll
    for (int ct = 0; ct < 4; ct++)
      #pragma unroll
      for (int r = 0; r < 4; r++){
        float e = exp2f(s[ct][r] - mrun);
        s[ct][r] = e;
        rs += e;
      }
    rs += __shfl_xor(rs, 16);
    rs += __shfl_xor(rs, 32);
    lrun += rs;

    // pack P to bf16 pairs: up[ct][h] covers kv pair-index 8ct+2g+h
    unsigned up[4][2];
    #pragma unroll
    for (int ct = 0; ct < 4; ct++)
      #pragma unroll
      for (int h = 0; h < 2; h++)
        up[ct][h] = (unsigned)f2bf(s[ct][2 * h]) |
                    ((unsigned)f2bf(s[ct][2 * h + 1]) << 16);
    // redistribute: pb[kc] slot j = kv pair 16kc+4g+j, from lane
    // g_s=(j+4(g&1))>>1, reg up[2kc+(g>>1)][j&1]
    union { unsigned u[2][4]; bf16x8 v[2]; } pb;
    #pragma unroll
    for (int kc = 0; kc < 2; kc++)
      #pragma unroll
      for (int j = 0; j < 4; j++){
        int src = (((j + ((g & 1) << 2)) >> 1) << 4) + l15;
        unsigned v0 = (unsigned)__shfl((int)up[2 * kc][j & 1], src);
        unsigned v1 = (unsigned)__shfl((int)up[2 * kc + 1][j & 1], src);
        pb.u[kc][j] = (g & 2) ? v1 : v0;
      }

    // O^T += V^T P
    __builtin_amdgcn_s_setprio(1);
    #pragma unroll
    for (int ct = 0; ct < 8; ct++){
      #pragma unroll
      for (int kc = 0; kc < 2; kc++){
        bf16x8 vf = *(const bf16x8*)(Vs + (16 * ct + l15) * 128 + (((4 * kc + g) ^ (l15 & 7)) << 4));
        ov[ct] = mfma16(vf, pb.v[kc], ov[ct]);
      }
    }
    __builtin_amdgcn_s_setprio(0);
  }
  // epilogue: unnormalized O~ + (m, l); lane holds channels 16ct+4g.. of q=l15
  size_t obase = (size_t)((sp * NB + n) * HW);
  size_t qrow = obase + q0 + 16 * w + l15;
  #pragma unroll
  for (int ct = 0; ct < 8; ct++){
    ushort4 pk;
    pk.x = f2bf(ov[ct][0]); pk.y = f2bf(ov[ct][1]);
    pk.z = f2bf(ov[ct][2]); pk.w = f2bf(ov[ct][3]);
    *(ushort4*)&Op[qrow * CCH + 16 * ct + 4 * g] = pk;
  }
  if (g == 0){
    Ml[qrow * 2]     = mrun;
    Ml[qrow * 2 + 1] = lrun;
  }
}

// ---------- Kernel E: combine splits + output projection + residual ----------
__global__ __launch_bounds__(256) void projout_k(const unsigned short* __restrict__ Op,
    const float* __restrict__ Ml, const unsigned short* __restrict__ wpb,
    const float* __restrict__ bp, const float* __restrict__ x,
    float* __restrict__ out, int splits){
  int n = blockIdx.y, l0 = blockIdx.x * 32, tid = threadIdx.x;
  int w = tid >> 6, lane = tid & 63, l15 = lane & 15, g = lane >> 4;
  __shared__ __align__(16) unsigned short hs[32][136];
  __shared__ __align__(16) char WB[32768];
  {
    const char* wb2 = (const char*)wpb;
    #pragma unroll
    for (int i = 0; i < 8; i++){
      int T = (8 * w + i) * 64 + lane;
      int row = T >> 4, c16 = (T & 15) ^ (row & 15);
      gll16(wb2 + row * 256 + c16 * 16, WB + (8 * w + i) * 1024);
    }
  }
  const size_t SSTR = (size_t)NB * HW;
  #pragma unroll
  for (int i = 0; i < 2; i++){
    int T = tid + 256 * i;
    int row = T >> 4, cb = (T & 15) * 8;
    size_t gl = (size_t)n * HW + l0 + row;
    float mv = -3.0e38f;
    #pragma unroll
    for (int s = 0; s < 8; s++)
      if (s < splits) mv = fmaxf(mv, Ml[(s * SSTR + gl) * 2]);
    float fa[8];
    #pragma unroll
    for (int j = 0; j < 8; j++) fa[j] = 0.f;
    float denom = 0.f;
    #pragma unroll
    for (int s = 0; s < 8; s++){
      if (s < splits){
        float wgt = exp2f(Ml[(s * SSTR + gl) * 2] - mv);   // log2-domain m
        denom += wgt * Ml[(s * SSTR + gl) * 2 + 1];
        uint4 a = *(const uint4*)&Op[(s * SSTR + gl) * CCH + cb];
        const unsigned short* au = (const unsigned short*)&a;
        #pragma unroll
        for (int j = 0; j < 8; j++) fa[j] += wgt * bf2f(au[j]);
      }
    }
    float inv = 1.f / denom;
    #pragma unroll
    for (int j = 0; j < 8; j++) hs[row][cb + j] = f2bf(fa[j] * inv);
  }
  __syncthreads();
  int rt = w & 1, cg = w >> 1;
  bf16x8 a[4];
  #pragma unroll
  for (int kc = 0; kc < 4; kc++)
    a[kc] = *reinterpret_cast<const bf16x8*>(&hs[16 * rt + l15][32 * kc + 8 * g]);
  f32x4 acc[4];
  #pragma unroll
  for (int ci = 0; ci < 4; ci++) acc[ci] = (f32x4)(0.f);
  #pragma unroll
  for (int ci = 0; ci < 4; ci++){
    int o = 16 * (cg * 4 + ci) + l15;
    #pragma unroll
    for (int kc = 0; kc < 4; kc++){
      bf16x8 bfr = *(const bf16x8*)(WB + o * 256 + ((4 * kc + g) ^ l15) * 16);
      acc[ci] = mfma16(a[kc], bfr, acc[ci]);
    }
  }
  #pragma unroll
  for (int ci = 0; ci < 4; ci++){
    int o = 16 * (cg * 4 + ci) + l15;
    float bias = bp[o];
    size_t base = ((size_t)(n * CCH) + o) * HW + l0 + 16 * rt + 4 * g;
    float4 xr = *(const float4*)&x[base];
    float4 res;
    res.x = xr.x + acc[ci][0] + bias;
    res.y = xr.y + acc[ci][1] + bias;
    res.z = xr.z + acc[ci][2] + bias;
    res.w = xr.w + acc[ci][3] + bias;
    *(float4*)&out[base] = res;
  }
}

extern "C" void kernel_launch(void* const* d_in, const int* in_sizes, int n_in,
                              void* d_out, int out_size, void* d_ws, size_t ws_size,
                              hipStream_t stream){
  const float* x    = (const float*)d_in[0];
  const float* gnsc = (const float*)d_in[1];
  const float* gnb  = (const float*)d_in[2];
  const float* wq   = (const float*)d_in[3];
  const float* bq   = (const float*)d_in[4];
  const float* wk   = (const float*)d_in[5];
  const float* bk   = (const float*)d_in[6];
  const float* wv   = (const float*)d_in[7];
  const float* bv   = (const float*)d_in[8];
  const float* wp   = (const float*)d_in[9];
  const float* bp   = (const float*)d_in[10];
  float* out = (float*)d_out;

  char* ws = (char*)d_ws;
  const size_t BUF = (size_t)NB * HW * CCH * sizeof(unsigned short);  // 4 MiB
  const size_t WOFF = 4096;
  const size_t QOFF = WOFF + 4 * 32768;   // after 4 bf16 weight mats
  const size_t MLSZ = (size_t)8 * NB * HW * 2 * sizeof(float);        // 1 MiB max
  const size_t NEED8 = QOFF + 3 * BUF + 8 * BUF + MLSZ;
  const size_t NEED4 = QOFF + 3 * BUF + 4 * BUF + MLSZ;
  const int lsp = (ws_size >= NEED8) ? 3 : ((ws_size >= NEED4) ? 2 : 1);
  const int splits = 1 << lsp;

  float* stats        = (float*)ws;
  unsigned short* wqb = (unsigned short*)(ws + WOFF);
  unsigned short* wkb = (unsigned short*)(ws + WOFF + 32768);
  unsigned short* wvb = (unsigned short*)(ws + WOFF + 65536);
  unsigned short* wpb = (unsigned short*)(ws + WOFF + 98304);
  unsigned short* Qg  = (unsigned short*)(ws + QOFF);
  unsigned short* Kg  = (unsigned short*)(ws + QOFF + BUF);
  unsigned short* Vt  = (unsigned short*)(ws + QOFF + 2 * BUF);
  unsigned short* Op  = (unsigned short*)(ws + QOFF + 3 * BUF);
  float*          Ml  = (float*)(ws + QOFF + 3 * BUF + (size_t)splits * BUF);

  gn_stats_k<<<128, 256, 0, stream>>>(x, stats, wq, wk, wv, wp, wqb, wkb, wvb, wpb);
  gnqkv_k<<<dim3(64, NB, 3), 256, 0, stream>>>(x, stats, gnsc, gnb,
      wqb, wkb, wvb, bq, bk, bv, Qg, Kg, Vt);
  attn_k<<<dim3(64 * NB * splits), 256, 0, stream>>>(Qg, Kg, Vt, Op, Ml, lsp);
  projout_k<<<dim3(128, NB), 256, 0, stream>>>(Op, Ml, wpb, bp, x, out, splits);
}

// Round 10
// 159.197 us; speedup vs baseline: 1.5175x; 1.0942x over previous
//
#include <hip/hip_runtime.h>

#define HW 4096
#define CCH 128
#define NB 4

typedef short bf16x8 __attribute__((ext_vector_type(8)));
typedef float f32x4 __attribute__((ext_vector_type(4)));

__device__ __forceinline__ unsigned short f2bf(float f){
  union { float fv; unsigned u; } v; v.fv = f;
  unsigned r = v.u + 0x7fffu + ((v.u >> 16) & 1u);
  return (unsigned short)(r >> 16);
}
__device__ __forceinline__ float bf2f(unsigned short u){
  return __uint_as_float(((unsigned)u) << 16);
}
__device__ __forceinline__ f32x4 mfma16(bf16x8 a, bf16x8 b, f32x4 c){
  return __builtin_amdgcn_mfma_f32_16x16x32_bf16(a, b, c, 0, 0, 0);
}
// packed f32x2 -> bf16x2 in one VALU op (lo = a, hi = b)
__device__ __forceinline__ unsigned cvt_pk(float a, float b){
  unsigned r;
  asm("v_cvt_pk_bf16_f32 %0, %1, %2" : "=v"(r) : "v"(a), "v"(b));
  return r;
}
// async global->LDS, 16B/lane; LDS dest = wave-uniform base + lane*16
__device__ __forceinline__ void gll16(const void* g, void* l){
  __builtin_amdgcn_global_load_lds(
      (const __attribute__((address_space(1))) unsigned*)g,
      (__attribute__((address_space(3))) unsigned*)l, 16, 0, 0);
}

// ---------- Kernel A: group-norm stats + weight fp32->bf16 prep ----------
__global__ __launch_bounds__(256) void gn_stats_k(const float* __restrict__ x,
    float* __restrict__ stats,
    const float* __restrict__ wq, const float* __restrict__ wk,
    const float* __restrict__ wv, const float* __restrict__ wp,
    unsigned short* __restrict__ wqb, unsigned short* __restrict__ wkb,
    unsigned short* __restrict__ wvb, unsigned short* __restrict__ wpb){
  int tid = threadIdx.x;
  if (tid < 128){
    int f4 = blockIdx.x * 128 + tid;
    int m = f4 >> 12, e = f4 & 4095;
    const float* s4 = (m == 0) ? wq : ((m == 1) ? wk : ((m == 2) ? wv : wp));
    unsigned short* d4 = (m == 0) ? wqb : ((m == 1) ? wkb : ((m == 2) ? wvb : wpb));
    float4 v = *(const float4*)(s4 + e * 4);
    ushort4 b; b.x = f2bf(v.x); b.y = f2bf(v.y); b.z = f2bf(v.z); b.w = f2bf(v.w);
    *(ushort4*)(d4 + e * 4) = b;
  }
  int gid = blockIdx.x;
  const float4* p = (const float4*)(x + (size_t)gid * 16384);
  float s = 0.f, q = 0.f;
  #pragma unroll
  for (int i = 0; i < 16; i++){
    float4 v = p[tid + 256 * i];
    s += v.x + v.y + v.z + v.w;
    q += v.x * v.x + v.y * v.y + v.z * v.z + v.w * v.w;
  }
  #pragma unroll
  for (int d = 1; d < 64; d <<= 1){ s += __shfl_xor(s, d); q += __shfl_xor(q, d); }
  __shared__ float red[8];
  int w = tid >> 6;
  if ((tid & 63) == 0){ red[2 * w] = s; red[2 * w + 1] = q; }
  __syncthreads();
  if (tid == 0){
    float S = red[0] + red[2] + red[4] + red[6];
    float Q = red[1] + red[3] + red[5] + red[7];
    float mean = S * (1.f / 16384.f);
    float var  = Q * (1.f / 16384.f) - mean * mean;
    stats[2 * gid]     = mean;
    stats[2 * gid + 1] = rsqrtf(var + 1e-5f);
  }
}

// ---------- Kernel B: fused GN-apply + QKV projection ----------
__global__ __launch_bounds__(256, 3) void gnqkv_k(const float* __restrict__ x,
    const float* __restrict__ stats, const float* __restrict__ sc,
    const float* __restrict__ bi,
    const unsigned short* __restrict__ wqb, const unsigned short* __restrict__ wkb,
    const unsigned short* __restrict__ wvb,
    const float* __restrict__ bq, const float* __restrict__ bk,
    const float* __restrict__ bv,
    unsigned short* __restrict__ Qg, unsigned short* __restrict__ Kg,
    unsigned short* __restrict__ Vt){
  int n = blockIdx.y, l0 = blockIdx.x * 64, m = blockIdx.z, tid = threadIdx.x;
  int w = tid >> 6, lane = tid & 63, l15 = lane & 15, g = lane >> 4;
  __shared__ __align__(16) char lds[49152];
  char* hA = lds;            // 16KB [64 l x 256B c], slot s holds c-chunk s^(l&15)
  char* WB = lds + 16384;    // 32KB [128 x 256B], slot s^(row&15)
  const unsigned short* wsrc = (m == 0) ? wqb : ((m == 1) ? wkb : wvb);
  const float* bsrc = (m == 0) ? bq : ((m == 1) ? bk : bv);
  {
    const char* wb2 = (const char*)wsrc;
    #pragma unroll
    for (int i = 0; i < 8; i++){
      int T = (8 * w + i) * 64 + lane;
      int row = T >> 4, c16 = (T & 15) ^ (row & 15);
      gll16(wb2 + row * 256 + c16 * 16, WB + (8 * w + i) * 1024);
    }
  }
  #pragma unroll
  for (int i = 0; i < 8; i++){
    int F = tid + 256 * i;
    int c = F >> 4, l4 = F & 15;
    float4 v = *(const float4*)&x[((size_t)(n * CCH + c)) * HW + l0 + l4 * 4];
    int grp = n * 32 + (c >> 2);
    float mean = stats[2 * grp], rstd = stats[2 * grp + 1];
    float scl = rstd * sc[c];
    float off = bi[c] - mean * scl;
    float r0 = v.x * scl + off, r1 = v.y * scl + off;
    float r2 = v.z * scl + off, r3 = v.w * scl + off;
    #pragma unroll
    for (int j = 0; j < 4; j++){
      int l = l4 * 4 + j;
      float rv = (j == 0) ? r0 : ((j == 1) ? r1 : ((j == 2) ? r2 : r3));
      int slot = (c >> 3) ^ (l & 15);
      *(unsigned short*)(hA + l * 256 + slot * 16 + ((c & 7) << 1)) = f2bf(rv);
    }
  }
  __syncthreads();
  bf16x8 a[4];
  #pragma unroll
  for (int kc = 0; kc < 4; kc++)
    a[kc] = *(const bf16x8*)(hA + (16 * w + l15) * 256 + ((4 * kc + g) ^ l15) * 16);
  f32x4 acc[8];
  #pragma unroll
  for (int ct = 0; ct < 8; ct++) acc[ct] = (f32x4)(0.f);
  #pragma unroll
  for (int ct = 0; ct < 8; ct++)
    #pragma unroll
    for (int kc = 0; kc < 4; kc++){
      bf16x8 bfr = *(const bf16x8*)(WB + (16 * ct + l15) * 256 + ((4 * kc + g) ^ l15) * 16);
      acc[ct] = mfma16(a[kc], bfr, acc[ct]);
    }
  __syncthreads();   // WB reads done; reuse as output-stage LDS
  if (m < 2){
    // Q pre-scale folds 128^-0.5 AND log2(e): softmax runs in exp2 domain
    float qs = (m == 0) ? (0.08838834764831845f * 1.4426950408889634f) : 1.0f;
    unsigned short* dst = (m == 0) ? Qg : Kg;
    unsigned short* os = (unsigned short*)(lds + 16384);  // [64][136]
    #pragma unroll
    for (int ct = 0; ct < 8; ct++){
      int o = 16 * ct + l15;
      float bias = bsrc[o];
      #pragma unroll
      for (int r = 0; r < 4; r++)
        os[(16 * w + 4 * g + r) * 136 + o] = f2bf((acc[ct][r] + bias) * qs);
    }
    __syncthreads();
    #pragma unroll
    for (int i = 0; i < 4; i++){
      int T = tid + 256 * i;
      int row = T >> 4, cb = T & 15;
      *(uint4*)&dst[((size_t)(n * HW) + l0 + row) * CCH + cb * 8] =
          *(const uint4*)&os[row * 136 + cb * 8];
    }
  } else {
    unsigned short* os = (unsigned short*)(lds + 16384);  // [128][72]
    #pragma unroll
    for (int ct = 0; ct < 8; ct++){
      int o = 16 * ct + l15;
      float bias = bsrc[o];
      #pragma unroll
      for (int r = 0; r < 4; r++)
        os[o * 72 + 16 * w + 4 * g + r] = f2bf(acc[ct][r] + bias);
    }
    __syncthreads();
    #pragma unroll
    for (int i = 0; i < 4; i++){
      int T = tid + 256 * i;
      int row = T >> 3, c = T & 7;
      *(uint4*)&Vt[((size_t)(n * CCH) + row) * HW + l0 + c * 8] =
          *(const uint4*)&os[row * 72 + c * 8];
    }
  }
}

// ---------- Kernel D: flash attention (R6 basin + exp2 + cvt_pk) ----------
// Swapped-operand QK^T = mfma(K,Q): lane holds S[q][kv=16ct+4g+r] in log2
// domain; softmax in-lane + 2 shfl; P in regs via cvt_pk + 16 shfl; PV =
// mfma(V^T,P). 32KB LDS, 2 barriers/iter, splits=4, 4 blocks/CU.
__global__ __launch_bounds__(256, 4) void attn_k(const unsigned short* __restrict__ Qg,
    const unsigned short* __restrict__ Kg, const unsigned short* __restrict__ Vt,
    unsigned short* __restrict__ Op, float* __restrict__ Ml, int lsp){
  int nbk = gridDim.x, cpx = nbk >> 3, b = blockIdx.x;
  int swz = (b & 7) * cpx + (b >> 3);
  int q0 = (swz & 63) * 64;
  int rest = swz >> 6;
  int splits = 1 << lsp;
  int sp = rest & (splits - 1);
  int n = rest >> lsp;
  int kvs = HW >> lsp, nt = 64 >> lsp;
  int tid = threadIdx.x;
  int w = tid >> 6, lane = tid & 63, l15 = lane & 15, g = lane >> 4;
  __shared__ __align__(16) char lds[32768];
  char* Ks = lds;            // 16 KB [64 x 256B], chunk swz c^(row&15)
  char* Vs = lds + 16384;    // 16 KB [128 x 128B], chunk swz c^(row&7)
  const float THR = 8.0f * 1.4426950408889634f;   // defer-rescale, log2 domain

  bf16x8 qf[4];   // lane holds Q[q=16w+l15][c=32kc+8g..] (log2e-prescaled)
  #pragma unroll
  for (int kc = 0; kc < 4; kc++)
    qf[kc] = *reinterpret_cast<const bf16x8*>(
        &Qg[((size_t)(n * HW) + q0 + 16 * w + l15) * CCH + 32 * kc + 8 * g]);
  f32x4 ov[8];    // ov[ct][r] = O[q][c=16ct+4g+r] (unnormalized)
  #pragma unroll
  for (int i = 0; i < 8; i++) ov[i] = (f32x4)(0.f);
  float mrun = -3.0e38f, lrun = 0.f;

  const char* kp[4]; const char* vp[4];
  {
    const char* kbase = (const char*)Kg + ((size_t)(n * HW) + sp * kvs) * (CCH * 2);
    const char* vbase = (const char*)Vt + (size_t)(n * CCH) * (HW * 2) + (size_t)sp * kvs * 2;
    #pragma unroll
    for (int i = 0; i < 4; i++){
      int C = (w * 4 + i) * 64 + lane;
      int row = C >> 4, c16 = (C & 15) ^ (row & 15);
      kp[i] = kbase + row * 256 + c16 * 16;
      int vrow = C >> 3, c8 = (C & 7) ^ (vrow & 7);
      vp[i] = vbase + (size_t)vrow * (HW * 2) + c8 * 16;
    }
  }
  char* kl = Ks + w * 4096;
  char* vl = Vs + w * 4096;

  for (int t = 0; t < nt; t++){
    __syncthreads();                 // B1: prev iter done with Ks/Vs
    #pragma unroll
    for (int i = 0; i < 4; i++) gll16(kp[i] + (size_t)t * 16384, kl + i * 1024);
    #pragma unroll
    for (int i = 0; i < 4; i++) gll16(vp[i] + (size_t)t * 128,   vl + i * 1024);
    __syncthreads();                 // B2: K/V tile visible

    // S^T (log2 domain): s[ct][r] = S[q][kv=16ct+4g+r]
    f32x4 s[4];
    __builtin_amdgcn_s_setprio(1);
    #pragma unroll
    for (int ct = 0; ct < 4; ct++){
      f32x4 acc = (f32x4)(0.f);
      #pragma unroll
      for (int kc = 0; kc < 4; kc++){
        bf16x8 kf = *(const bf16x8*)(Ks + (16 * ct + l15) * 256 + (((4 * kc + g) ^ l15) << 4));
        acc = mfma16(kf, qf[kc], acc);   // swapped operands
      }
      s[ct] = acc;
    }
    __builtin_amdgcn_s_setprio(0);

    // in-lane softmax (16 scores) + 2-shfl reduce; exp2 throughout
    float mx = -3.0e38f;
    #pragma unroll
    for (int ct = 0; ct < 4; ct++)
      #pragma unroll
      for (int r = 0; r < 4; r++) mx = fmaxf(mx, s[ct][r]);
    mx = fmaxf(mx, __shfl_xor(mx, 16));
    mx = fmaxf(mx, __shfl_xor(mx, 32));
    if (__any(mx > mrun + THR)){     // defer-rescale
      float mn = fmaxf(mrun, mx);
      float al = exp2f(mrun - mn);
      mrun = mn; lrun *= al;
      #pragma unroll
      for (int ct = 0; ct < 8; ct++)
        #pragma unroll
        for (int r = 0; r < 4; r++) ov[ct][r] *= al;
    }
    float rs = 0.f;
    #pragma unroll
    for (int ct = 0; ct < 4; ct++)
      #pragma unroll
      for (int r = 0; r < 4; r++){
        float e = exp2f(s[ct][r] - mrun);
        s[ct][r] = e;
        rs += e;
      }
    rs += __shfl_xor(rs, 16);
    rs += __shfl_xor(rs, 32);
    lrun += rs;

    // pack P to bf16 pairs via cvt_pk: up[ct][h] covers kv pair 8ct+2g+h
    unsigned up[4][2];
    #pragma unroll
    for (int ct = 0; ct < 4; ct++)
      #pragma unroll
      for (int h = 0; h < 2; h++)
        up[ct][h] = cvt_pk(s[ct][2 * h], s[ct][2 * h + 1]);
    // redistribute: pb[kc] slot j = kv pair 16kc+4g+j, from lane
    // g_s=(j+4(g&1))>>1, reg up[2kc+(g>>1)][j&1]
    union { unsigned u[2][4]; bf16x8 v[2]; } pb;
    #pragma unroll
    for (int kc = 0; kc < 2; kc++)
      #pragma unroll
      for (int j = 0; j < 4; j++){
        int src = (((j + ((g & 1) << 2)) >> 1) << 4) + l15;
        unsigned v0 = (unsigned)__shfl((int)up[2 * kc][j & 1], src);
        unsigned v1 = (unsigned)__shfl((int)up[2 * kc + 1][j & 1], src);
        pb.u[kc][j] = (g & 2) ? v1 : v0;
      }

    // O^T += V^T P
    __builtin_amdgcn_s_setprio(1);
    #pragma unroll
    for (int ct = 0; ct < 8; ct++){
      #pragma unroll
      for (int kc = 0; kc < 2; kc++){
        bf16x8 vf = *(const bf16x8*)(Vs + (16 * ct + l15) * 128 + (((4 * kc + g) ^ (l15 & 7)) << 4));
        ov[ct] = mfma16(vf, pb.v[kc], ov[ct]);
      }
    }
    __builtin_amdgcn_s_setprio(0);
  }
  // epilogue: unnormalized O~ (cvt_pk packed) + (m, l)
  size_t obase = (size_t)((sp * NB + n) * HW);
  size_t qrow = obase + q0 + 16 * w + l15;
  #pragma unroll
  for (int ct = 0; ct < 8; ct++){
    uint2 pk;
    pk.x = cvt_pk(ov[ct][0], ov[ct][1]);
    pk.y = cvt_pk(ov[ct][2], ov[ct][3]);
    *(uint2*)&Op[qrow * CCH + 16 * ct + 4 * g] = pk;
  }
  if (g == 0){
    Ml[qrow * 2]     = mrun;
    Ml[qrow * 2 + 1] = lrun;
  }
}

// ---------- Kernel E: combine splits + output projection + residual ----------
__global__ __launch_bounds__(256) void projout_k(const unsigned short* __restrict__ Op,
    const float* __restrict__ Ml, const unsigned short* __restrict__ wpb,
    const float* __restrict__ bp, const float* __restrict__ x,
    float* __restrict__ out, int splits){
  int n = blockIdx.y, l0 = blockIdx.x * 32, tid = threadIdx.x;
  int w = tid >> 6, lane = tid & 63, l15 = lane & 15, g = lane >> 4;
  __shared__ __align__(16) unsigned short hs[32][136];
  __shared__ __align__(16) char WB[32768];
  {
    const char* wb2 = (const char*)wpb;
    #pragma unroll
    for (int i = 0; i < 8; i++){
      int T = (8 * w + i) * 64 + lane;
      int row = T >> 4, c16 = (T & 15) ^ (row & 15);
      gll16(wb2 + row * 256 + c16 * 16, WB + (8 * w + i) * 1024);
    }
  }
  const size_t SSTR = (size_t)NB * HW;
  #pragma unroll
  for (int i = 0; i < 2; i++){
    int T = tid + 256 * i;
    int row = T >> 4, cb = (T & 15) * 8;
    size_t gl = (size_t)n * HW + l0 + row;
    float mv = -3.0e38f;
    #pragma unroll
    for (int s = 0; s < 4; s++)
      if (s < splits) mv = fmaxf(mv, Ml[(s * SSTR + gl) * 2]);
    float fa[8];
    #pragma unroll
    for (int j = 0; j < 8; j++) fa[j] = 0.f;
    float denom = 0.f;
    #pragma unroll
    for (int s = 0; s < 4; s++){
      if (s < splits){
        float wgt = exp2f(Ml[(s * SSTR + gl) * 2] - mv);   // log2-domain m
        denom += wgt * Ml[(s * SSTR + gl) * 2 + 1];
        uint4 a = *(const uint4*)&Op[(s * SSTR + gl) * CCH + cb];
        const unsigned short* au = (const unsigned short*)&a;
        #pragma unroll
        for (int j = 0; j < 8; j++) fa[j] += wgt * bf2f(au[j]);
      }
    }
    float inv = 1.f / denom;
    #pragma unroll
    for (int j = 0; j < 8; j++) hs[row][cb + j] = f2bf(fa[j] * inv);
  }
  __syncthreads();
  int rt = w & 1, cg = w >> 1;
  bf16x8 a[4];
  #pragma unroll
  for (int kc = 0; kc < 4; kc++)
    a[kc] = *reinterpret_cast<const bf16x8*>(&hs[16 * rt + l15][32 * kc + 8 * g]);
  f32x4 acc[4];
  #pragma unroll
  for (int ci = 0; ci < 4; ci++) acc[ci] = (f32x4)(0.f);
  #pragma unroll
  for (int ci = 0; ci < 4; ci++){
    int o = 16 * (cg * 4 + ci) + l15;
    #pragma unroll
    for (int kc = 0; kc < 4; kc++){
      bf16x8 bfr = *(const bf16x8*)(WB + o * 256 + ((4 * kc + g) ^ l15) * 16);
      acc[ci] = mfma16(a[kc], bfr, acc[ci]);
    }
  }
  #pragma unroll
  for (int ci = 0; ci < 4; ci++){
    int o = 16 * (cg * 4 + ci) + l15;
    float bias = bp[o];
    size_t base = ((size_t)(n * CCH) + o) * HW + l0 + 16 * rt + 4 * g;
    float4 xr = *(const float4*)&x[base];
    float4 res;
    res.x = xr.x + acc[ci][0] + bias;
    res.y = xr.y + acc[ci][1] + bias;
    res.z = xr.z + acc[ci][2] + bias;
    res.w = xr.w + acc[ci][3] + bias;
    *(float4*)&out[base] = res;
  }
}

extern "C" void kernel_launch(void* const* d_in, const int* in_sizes, int n_in,
                              void* d_out, int out_size, void* d_ws, size_t ws_size,
                              hipStream_t stream){
  const float* x    = (const float*)d_in[0];
  const float* gnsc = (const float*)d_in[1];
  const float* gnb  = (const float*)d_in[2];
  const float* wq   = (const float*)d_in[3];
  const float* bq   = (const float*)d_in[4];
  const float* wk   = (const float*)d_in[5];
  const float* bk   = (const float*)d_in[6];
  const float* wv   = (const float*)d_in[7];
  const float* bv   = (const float*)d_in[8];
  const float* wp   = (const float*)d_in[9];
  const float* bp   = (const float*)d_in[10];
  float* out = (float*)d_out;

  char* ws = (char*)d_ws;
  const size_t BUF = (size_t)NB * HW * CCH * sizeof(unsigned short);  // 4 MiB
  const size_t WOFF = 4096;
  const size_t QOFF = WOFF + 4 * 32768;   // after 4 bf16 weight mats
  const size_t MLSZ = (size_t)4 * NB * HW * 2 * sizeof(float);        // 512 KiB max
  const size_t NEED4 = QOFF + 3 * BUF + 4 * BUF + MLSZ;
  const int lsp = (ws_size >= NEED4) ? 2 : 1;
  const int splits = 1 << lsp;

  float* stats        = (float*)ws;
  unsigned short* wqb = (unsigned short*)(ws + WOFF);
  unsigned short* wkb = (unsigned short*)(ws + WOFF + 32768);
  unsigned short* wvb = (unsigned short*)(ws + WOFF + 65536);
  unsigned short* wpb = (unsigned short*)(ws + WOFF + 98304);
  unsigned short* Qg  = (unsigned short*)(ws + QOFF);
  unsigned short* Kg  = (unsigned short*)(ws + QOFF + BUF);
  unsigned short* Vt  = (unsigned short*)(ws + QOFF + 2 * BUF);
  unsigned short* Op  = (unsigned short*)(ws + QOFF + 3 * BUF);
  float*          Ml  = (float*)(ws + QOFF + 3 * BUF + (size_t)splits * BUF);

  gn_stats_k<<<128, 256, 0, stream>>>(x, stats, wq, wk, wv, wp, wqb, wkb, wvb, wpb);
  gnqkv_k<<<dim3(64, NB, 3), 256, 0, stream>>>(x, stats, gnsc, gnb,
      wqb, wkb, wvb, bq, bk, bv, Qg, Kg, Vt);
  attn_k<<<dim3(64 * NB * splits), 256, 0, stream>>>(Qg, Kg, Vt, Op, Ml, lsp);
  projout_k<<<dim3(128, NB), 256, 0, stream>>>(Op, Ml, wpb, bp, x, out, splits);
}